// Round 3
// baseline (7268.374 us; speedup 1.0000x reference)
//
#include <hip/hip_runtime.h>
#include <cstdint>
#include <cstddef>
#include <type_traits>

// LSTM decoder: SEQ=256 steps, BATCH=256, HID=1024, OUT=512. f32 in/out.
// Folded recurrence: x_{t+1} = c_{t+1} @ W_out^T + b_out is folded into the
// gate GEMM via Wc2 = W_ih @ W_out, so each step is ONE GEMM
//   gates = [h | c] @ [W_hh | Wc2]^T  (M=256, N=4096, K=2048, bf16 MFMA)
// with the LSTM cell update fused into the epilogue (f32 cell master).
// All o_t outputs are one big GEMM at the end: outs = cs @ W_out^T + b_out.
//
// d_out is FLOAT32 (reference output dtype). Scratch lives in the `outs`
// third of d_out (128 MB, only written by the final GEMM); d_ws unused.

#define SEQ    256
#define BATCH  256
#define HID    1024
#define OUTD   512
#define KDIM   2048   // [h (1024) | c (1024)]
#define GATES  4096   // 4*HID, gate order i,f,g,o

typedef __bf16 bf16x8 __attribute__((ext_vector_type(8)));
typedef float  f32x4  __attribute__((ext_vector_type(4)));

__device__ __forceinline__ unsigned short f2bf(float x) {
  unsigned u = __float_as_uint(x);
  u = (u + 0x7FFFu + ((u >> 16) & 1u)) >> 16;   // RNE
  return (unsigned short)u;
}

__device__ __forceinline__ f32x4 mfma16(bf16x8 a, bf16x8 b, f32x4 c) {
  return __builtin_amdgcn_mfma_f32_16x16x32_bf16(a, b, c, 0, 0, 0);
}

__device__ __forceinline__ bf16x8 ld_frag_bf(const unsigned short* p) {
  uint4 u = *reinterpret_cast<const uint4*>(p);
  return __builtin_bit_cast(bf16x8, u);
}

// load 8 consecutive elements as a bf16x8 fragment; AT = ushort (bf16) or f32
template <typename AT>
__device__ __forceinline__ bf16x8 ld_frag(const AT* p) {
  if constexpr (std::is_same_v<AT, float>) {
    const float4 f0 = *reinterpret_cast<const float4*>(p);
    const float4 f1 = *reinterpret_cast<const float4*>(p + 4);
    uint4 v;
    v.x = (unsigned)f2bf(f0.x) | ((unsigned)f2bf(f0.y) << 16);
    v.y = (unsigned)f2bf(f0.z) | ((unsigned)f2bf(f0.w) << 16);
    v.z = (unsigned)f2bf(f1.x) | ((unsigned)f2bf(f1.y) << 16);
    v.w = (unsigned)f2bf(f1.z) | ((unsigned)f2bf(f1.w) << 16);
    return __builtin_bit_cast(bf16x8, v);
  } else {
    return ld_frag_bf(p);
  }
}

// ---------------- prep kernels ----------------

// W_hh (4096x1024 f32) -> bf16 into Wg2[n][0:1024] (row stride KDIM)
__global__ void k_cast_whh(const float* __restrict__ whh, unsigned short* __restrict__ wg2) {
  int i4 = blockIdx.x * blockDim.x + threadIdx.x;
  if (i4 >= (GATES * HID) / 4) return;
  int idx = i4 * 4;
  int n = idx >> 10, k = idx & 1023;
  const float4 v = *reinterpret_cast<const float4*>(whh + idx);
  ushort4 o; o.x = f2bf(v.x); o.y = f2bf(v.y); o.z = f2bf(v.z); o.w = f2bf(v.w);
  *reinterpret_cast<ushort4*>(wg2 + (size_t)n * KDIM + k) = o;
}

// W_out (512x1024 f32) -> transpose to WoTT bf16 [1024][512] (= W_out^T)
__global__ void k_cast_wout(const float* __restrict__ wout,
                            unsigned short* __restrict__ wott) {
  int idx = blockIdx.x * blockDim.x + threadIdx.x;
  if (idx >= OUTD * HID) return;
  int j = idx >> 10, k = idx & 1023;
  wott[(size_t)k * OUTD + j] = f2bf(wout[idx]);
}

// A0 = [bf16(c_vector) | 0], cbuf = c_vector (f32 master cell state)
__global__ void k_init(const float* __restrict__ cvec,
                       unsigned short* __restrict__ a0, float* __restrict__ cbuf) {
  int idx = blockIdx.x * blockDim.x + threadIdx.x;
  if (idx >= BATCH * KDIM) return;
  int b = idx >> 11, k = idx & 2047;
  if (k < HID) {
    float v = cvec[(size_t)b * HID + k];
    a0[idx] = f2bf(v);
    cbuf[(size_t)b * HID + k] = v;
  } else {
    a0[idx] = 0;
  }
}

// bias0[n] = b_ih+b_hh ; bias2[n] = bias0[n] + dot(W_ih[n,:], b_out)
__global__ void k_bias(const float* __restrict__ wih, const float* __restrict__ b_ih,
                       const float* __restrict__ b_hh, const float* __restrict__ b_out,
                       float* __restrict__ bias0, float* __restrict__ bias2) {
  int wave = threadIdx.x >> 6, l = threadIdx.x & 63;
  int n = blockIdx.x * 4 + wave;
  float s = 0.f;
  for (int j = l; j < OUTD; j += 64) s += wih[(size_t)n * OUTD + j] * b_out[j];
  for (int off = 32; off; off >>= 1) s += __shfl_down(s, off);
  if (l == 0) {
    float b0 = b_ih[n] + b_hh[n];
    bias0[n] = b0;
    bias2[n] = b0 + s;
  }
}

// ---------------- generic bf16-MFMA GEMM (f32 or bf16 operands) ----------
// D[m][c] = sum_k A[m][k] * Bn[c][k]  (+ bias[c]).
// A row-major [M][lda] (AT = f32 or bf16-ushort); Bn "n-major" [N][ldb]
// (BT = f32 or bf16-ushort, converted during LDS staging); D (DT = f32 or
// bf16-ushort). Tile 64(m)x64(n) per WG, 4 waves; B staged in LDS
// (64 cols x 512 k bf16), XOR-swizzled 16B chunks. K % 512 == 0.
// Grid: x = n-blocks, y = m-blocks (consecutive blocks share the A panel).
template <typename AT, typename BT, typename DT>
__global__ __launch_bounds__(256)
void k_gemm(const AT* __restrict__ A, int lda,
            const BT* __restrict__ Bn, int ldb,
            DT* __restrict__ D, int ldd,
            const float* __restrict__ bias, int K) {
  __shared__ char lds[64 * 1024];
  const int tid = threadIdx.x;
  const int w = tid >> 6, l = tid & 63;
  const int n0 = blockIdx.x * 64;
  const int m0 = blockIdx.y * 64 + w * 16;
  const int lr = l & 15, lg = l >> 4;

  f32x4 acc[4] = {};
  for (int kc = 0; kc < K; kc += 512) {
    __syncthreads();
    for (int it = 0; it < 16; ++it) {
      int idx = tid + it * 256;
      int col = idx >> 6, k16 = idx & 63;
      uint4 v;
      if constexpr (std::is_same_v<BT, float>) {
        const float* src = Bn + (size_t)(n0 + col) * ldb + kc + k16 * 8;
        const float4 f0 = *reinterpret_cast<const float4*>(src);
        const float4 f1 = *reinterpret_cast<const float4*>(src + 4);
        v.x = (unsigned)f2bf(f0.x) | ((unsigned)f2bf(f0.y) << 16);
        v.y = (unsigned)f2bf(f0.z) | ((unsigned)f2bf(f0.w) << 16);
        v.z = (unsigned)f2bf(f1.x) | ((unsigned)f2bf(f1.y) << 16);
        v.w = (unsigned)f2bf(f1.z) | ((unsigned)f2bf(f1.w) << 16);
      } else {
        v = *reinterpret_cast<const uint4*>(Bn + (size_t)(n0 + col) * ldb + kc + k16 * 8);
      }
      int db = col * 1024 + ((k16 * 16) ^ ((col & 7) << 4));
      *reinterpret_cast<uint4*>(lds + db) = v;
    }
    __syncthreads();
    const AT* Arow = A + (size_t)(m0 + lr) * lda + kc + lg * 8;
#pragma unroll
    for (int ks = 0; ks < 16; ++ks) {
      bf16x8 af = ld_frag(Arow + ks * 32);
      int kb = ks * 64 + lg * 16;
#pragma unroll
      for (int f = 0; f < 4; ++f) {
        int col = f * 16 + lr;
        uint4 u = *reinterpret_cast<const uint4*>(lds + col * 1024 + (kb ^ ((col & 7) << 4)));
        acc[f] = mfma16(af, __builtin_bit_cast(bf16x8, u), acc[f]);
      }
    }
  }
#pragma unroll
  for (int f = 0; f < 4; ++f) {
    int cg = n0 + f * 16 + lr;
    float bv = bias ? bias[cg] : 0.f;
#pragma unroll
    for (int j = 0; j < 4; ++j) {
      int r = m0 + lg * 4 + j;
      float val = acc[f][j] + bv;
      if constexpr (std::is_same_v<DT, unsigned short>) {
        D[(size_t)r * ldd + cg] = f2bf(val);
      } else {
        D[(size_t)r * ldd + cg] = val;
      }
    }
  }
}

// ---------------- fused LSTM step ----------------
// gates = A(cur) @ Wg2^T + bias, then cell update. Grid: 256 WGs =
// 4 m-groups x 64 col-groups; each WG: 64 rows x (4 gates x 16 hidden cols).
// hs/cs written as FLOAT32 (d_out dtype); cell state kept in f32 cbuf.
__global__ __launch_bounds__(256)
void k_step(const unsigned short* __restrict__ Acur,
            unsigned short* __restrict__ Anext,
            float* __restrict__ cbuf,
            const unsigned short* __restrict__ Wg2,
            const float* __restrict__ bias,
            float* __restrict__ hs,
            float* __restrict__ cs,
            int t) {
  __shared__ char lds[64 * 1024];
  const int tid = threadIdx.x;
  const int w = tid >> 6, l = tid & 63;
  const int m0 = (blockIdx.x & 3) * 64 + w * 16;
  const int n0 = (blockIdx.x >> 2) * 16;
  const int lr = l & 15, lg = l >> 4;

  f32x4 acc[4] = {};
  for (int kc = 0; kc < KDIM; kc += 512) {
    __syncthreads();
    for (int it = 0; it < 16; ++it) {
      int idx = tid + it * 256;
      int col = idx >> 6, k16 = idx & 63;              // col = gate*16 + cc
      int grow = (col >> 4) * HID + n0 + (col & 15);   // global gate row
      const uint4 v = *reinterpret_cast<const uint4*>(Wg2 + (size_t)grow * KDIM + kc + k16 * 8);
      int db = col * 1024 + ((k16 * 16) ^ ((col & 7) << 4));
      *reinterpret_cast<uint4*>(lds + db) = v;
    }
    __syncthreads();
    const unsigned short* Arow = Acur + (size_t)(m0 + lr) * KDIM + kc + lg * 8;
#pragma unroll
    for (int ks = 0; ks < 16; ++ks) {
      bf16x8 af = ld_frag_bf(Arow + ks * 32);
      int kb = ks * 64 + lg * 16;
#pragma unroll
      for (int f = 0; f < 4; ++f) {
        int col = f * 16 + lr;
        uint4 u = *reinterpret_cast<const uint4*>(lds + col * 1024 + (kb ^ ((col & 7) << 4)));
        acc[f] = mfma16(af, __builtin_bit_cast(bf16x8, u), acc[f]);
      }
    }
  }
  // epilogue: acc[0..3] = i,f,g,o preacts for hidden col n, rows m0+lg*4+j
  const int n = n0 + lr;
  const float bi = bias[n], bff = bias[n + HID], bg = bias[n + 2 * HID], bo = bias[n + 3 * HID];
#pragma unroll
  for (int j = 0; j < 4; ++j) {
    int b = m0 + lg * 4 + j;
    float gi = acc[0][j] + bi;
    float gf = acc[1][j] + bff;
    float gg = acc[2][j] + bg;
    float go = acc[3][j] + bo;
    float si = 1.f / (1.f + __expf(-gi));
    float sf = 1.f / (1.f + __expf(-gf));
    float so = 1.f / (1.f + __expf(-go));
    float tg = tanhf(gg);
    float co = cbuf[(size_t)b * HID + n];
    float cn = sf * co + si * tg;
    float hn = so * tanhf(cn);
    cbuf[(size_t)b * HID + n] = cn;
    Anext[(size_t)b * KDIM + n] = f2bf(hn);
    Anext[(size_t)b * KDIM + HID + n] = f2bf(cn);
    size_t o = (size_t)b * (SEQ * HID) + (size_t)t * HID + n;
    hs[o] = hn;
    cs[o] = cn;
  }
}

// ---------------- launch ----------------
extern "C" void kernel_launch(void* const* d_in, const int* in_sizes, int n_in,
                              void* d_out, int out_size, void* d_ws, size_t ws_size,
                              hipStream_t stream) {
  const float* c_vec = (const float*)d_in[0];
  const float* W_ih  = (const float*)d_in[1];
  const float* W_hh  = (const float*)d_in[2];
  const float* b_ih  = (const float*)d_in[3];
  const float* b_hh  = (const float*)d_in[4];
  const float* W_out = (const float*)d_in[5];
  const float* b_out = (const float*)d_in[6];

  float* out = (float*)d_out;                          // f32 output buffer
  float* hs = out;                                     // [B][T][H]
  float* cs = out + (size_t)BATCH * SEQ * HID;         // [B][T][H]
  float* os = out + (size_t)2 * BATCH * SEQ * HID;     // [B][T][OUT]

  // Scratch in the `outs` region of d_out (128 MB as f32; only written by
  // the final GEMM, which reads nothing from it). d_ws unused.
  char* sc = (char*)os;
  unsigned short* Wg2  = (unsigned short*)(sc);                 // [4096][2048] bf16, 16 MB
  unsigned short* WoTT = (unsigned short*)(sc + (16u << 20));   // [1024][512] bf16 (W_out^T), 1 MB
  unsigned short* A0   = (unsigned short*)(sc + (17u << 20));   // [256][2048] bf16, 1 MB
  unsigned short* A1   = (unsigned short*)(sc + (18u << 20));   // 1 MB
  float*          cbuf = (float*)(sc + (19u << 20));            // [256][1024] f32, 1 MB
  float*          bias0 = (float*)(sc + (20u << 20));           // 16 KB
  float*          bias2 = (float*)(sc + (20u << 20) + 16384);   // 16 KB
  // total scratch ~20 MB < 128 MB available

  k_cast_whh<<<dim3(GATES * HID / 4 / 256), dim3(256), 0, stream>>>(W_hh, Wg2);
  k_cast_wout<<<dim3(OUTD * HID / 256), dim3(256), 0, stream>>>(W_out, WoTT);
  k_init<<<dim3(BATCH * KDIM / 256), dim3(256), 0, stream>>>(c_vec, A0, cbuf);
  k_bias<<<dim3(GATES / 4), dim3(256), 0, stream>>>(W_ih, b_ih, b_hh, b_out, bias0, bias2);
  // Wc2 = W_ih @ W_out -> Wg2[:, 1024:2048]   (A = W_ih f32 direct, B = WoTT bf16)
  k_gemm<float, unsigned short, unsigned short>
      <<<dim3(HID / 64, GATES / 64), dim3(256), 0, stream>>>(
      W_ih, OUTD, WoTT, OUTD, Wg2 + HID, KDIM, (const float*)nullptr, OUTD);
  // recurrence: one fused kernel per step
  unsigned short* Ap[2] = {A0, A1};
  for (int t = 0; t < SEQ; ++t) {
    k_step<<<dim3(256), dim3(256), 0, stream>>>(
        Ap[t & 1], Ap[(t + 1) & 1], cbuf, Wg2,
        (t == 0) ? bias0 : bias2, hs, cs, t);
  }
  // outs = cs @ W_out^T + b_out  (M = BATCH*SEQ = 65536, N = 512, K = 1024)
  // A = cs (f32, in d_out, read-only here), B = W_out f32 (already n-major).
  k_gemm<float, float, float>
      <<<dim3(OUTD / 64, BATCH * SEQ / 64), dim3(256), 0, stream>>>(
      cs, HID, W_out, HID, os, OUTD, b_out, HID);
}